// Round 4
// baseline (537.738 us; speedup 1.0000x reference)
//
#include <hip/hip_runtime.h>

// RelativePositionEncoding: out[1,1024,1024,128] f32 (537 MB, write-bound).
// out[i,j,:] = W_si[d_si] + W_ti[d_ti] + bent*w_ent + W_sym[d_sym]
// R3: per-block folded LDS tables -> hot loop is 2 ds_read_b128 + 1 nt store,
// no data-dependent global loads (R1/R2 were gated on L2-latency W loads).
//   tab_si[d]  = W_si[d] + W_ti[65]            (d_ti==65 unless color&index match, P~1/4096)
//   tab_sym[s] = W_sym[s] + w_ent (s<5), W_sym[5] (s==5)   (bent=1 <=> dsym<5)
// Rare dti!=65 handled on a cold branch with a +Wti[dti]-Wti[65] correction.

#define SEQ_L 1024
#define NW4   32   // float4 per 128-dim row

typedef float vf4 __attribute__((ext_vector_type(4)));

__global__ __launch_bounds__(256, 4)
void rpe_kernel(const int* __restrict__ seq_index,
                const int* __restrict__ seq_color,
                const int* __restrict__ seq_sym,
                const int* __restrict__ seq_entity,
                const int* __restrict__ token_index,
                const float* __restrict__ W,
                float* __restrict__ out)
{
    __shared__ vf4 tab_si[66 * NW4];   // 33,792 B
    __shared__ vf4 tab_sym[6 * NW4];   //  3,072 B
    __shared__ int bins[SEQ_L];        //  4,096 B  -> 40,960 B total (4 blocks/CU)

    const int t = threadIdx.x;
    const int i = blockIdx.x;

    // Per-row (i) values — wave-uniform -> scalar loads.
    const int si_i  = seq_index[i];
    const int col_i = seq_color[i];
    const int sym_i = seq_sym[i];
    const int ent_i = seq_entity[i];
    const int ti_i  = token_index[i];

    const vf4* W4 = (const vf4*)W;

    // Build folded tables (W is L2-hot; 36 KB of reads per block).
    for (int idx = t; idx < 66 * NW4; idx += 256) {
        const int d = idx >> 5, g = idx & 31;
        tab_si[idx] = W4[d * NW4 + g] + W4[(66 + 65) * NW4 + g];
    }
    for (int idx = t; idx < 6 * NW4; idx += 256) {
        const int s = idx >> 5, g = idx & 31;
        vf4 v = W4[(133 + s) * NW4 + g];
        if (s < 5) v += W4[132 * NW4 + g];   // + w_ent (bent=1 case)
        tab_sym[idx] = v;
    }

    // Precompute packed bins for every j (once per block).
    for (int j = t; j < SEQ_L; j += 256) {
        const int cj = seq_color[j];
        const int sj = seq_index[j];
        const int ej = seq_entity[j];
        int dsi = 65, dsym = 5, dti = 0, rare = 0;
        if (cj == col_i) {
            int d = si_i - sj;
            dsi = min(max(d, -32), 32) + 32;
            if (sj == si_i) {
                int dt = ti_i - token_index[j];
                dti = min(max(dt, -32), 32) + 32;
                rare = 1;
            }
        }
        if (ej == ent_i) {
            int ds = sym_i - seq_sym[j];
            dsym = min(max(ds, -2), 2) + 2;
        }
        bins[j] = dsi | (dsym << 8) | (dti << 16) | (rare << 24);
    }
    __syncthreads();

    const int g  = t & 31;   // which float4 of the 32 covering 128 dims
    const int j0 = t >> 5;   // 2 j's per wave per iter, 8 per block-iter

    vf4* out4 = (vf4*)out + (size_t)i * (SEQ_L * NW4);

    #pragma unroll 4
    for (int j = j0; j < SEQ_L; j += 8) {
        const int pack = bins[j];
        vf4 r = tab_si[(pack & 0xff) * NW4 + g]
              + tab_sym[((pack >> 8) & 0xff) * NW4 + g];
        if (pack & (1 << 24)) {                 // ~1/4096 of j's: dti != 65
            const int dti = (pack >> 16) & 0xff;
            r += W4[(66 + dti) * NW4 + g] - W4[(66 + 65) * NW4 + g];
        }
        __builtin_nontemporal_store(r, &out4[j * NW4 + g]);
    }
}

extern "C" void kernel_launch(void* const* d_in, const int* in_sizes, int n_in,
                              void* d_out, int out_size, void* d_ws, size_t ws_size,
                              hipStream_t stream) {
    const int*   seq_index   = (const int*)d_in[0];
    const int*   seq_color   = (const int*)d_in[1];
    const int*   seq_sym     = (const int*)d_in[2];
    const int*   seq_entity  = (const int*)d_in[3];
    const int*   token_index = (const int*)d_in[4];
    const float* W           = (const float*)d_in[5];
    float*       out         = (float*)d_out;

    rpe_kernel<<<SEQ_L, 256, 0, stream>>>(seq_index, seq_color, seq_sym,
                                          seq_entity, token_index, W, out);
}